// Round 3
// baseline (193.631 us; speedup 1.0000x reference)
//
#include <hip/hip_runtime.h>

// ============================================================================
// R15: j-split, zero-barrier tile loop — FIXED LDS sizing (R14's bug: W2/Wc
// are 32768 B each, not 16384; staging overflowed into ms -> NaN).
// Structure: 512 threads / 8 waves per block; wave w owns j-rows
// [32w, 32w+32) (two 16-col B-frags) x ALL 128 fo. TJ=256, 2 tiles.
//   - m1 built directly in registers as MFMA B-frags (no m1s LDS)
//   - each weight A-frag LDS read feeds 2 MFMAs (j-unroll) -> wgt traffic /2
//   - ms rows wave-private (in-order DS within wave; no barriers)
//   - agg/cs combined once post-loop
// LDS = 138240 B -> 1 block/CU -> 8 waves/CU (2/SIMD), barrier-free loop.
// Math identical to R13 (CM-scaled silu algebra; same prep kernel, same
// verified frag layouts).
//
// __launch_bounds__ 2nd-arg EMPIRICAL RULE (this toolchain, gfx950):
//   (256,4)/(512,4) -> 64-VGPR cap, catastrophic spill. (512,2) safe.
// ============================================================================

#define B_ 2
#define N_ 512
#define F_ 128
#define TJ 256      // j-rows per tile (32 per wave)
#define MSTRIDE 136 // shorts per LDS row: 128 + 8 pad (16B-aligned rows)

#define CM   (-1.44269504088896340736f)   // -log2(e)
#define INVC (-0.69314718055994530942f)   // 1/CM = -ln2

typedef __attribute__((ext_vector_type(8))) short short8;
typedef __attribute__((ext_vector_type(4))) float floatx4;
typedef __attribute__((ext_vector_type(2))) float floatx2;

#if defined(__has_builtin)
#if __has_builtin(__builtin_amdgcn_exp2f)
#define EXP2F(x) __builtin_amdgcn_exp2f(x)
#endif
#endif
#ifndef EXP2F
#define EXP2F(x) __expf((x) * 0.69314718055994530942f)
#endif

__device__ __forceinline__ float fsilu(float x) {  // tail-only
    float e = __expf(-x);
    return x * __builtin_amdgcn_rcpf(1.0f + e);
}
__device__ __forceinline__ floatx2 mk2(float a, float b) {
    floatx2 r; r.x = a; r.y = b; return r;
}
// y = CM*x. Returns CM*silu(x), pairwise. 1 trans + packable full-rate ops.
__device__ __forceinline__ floatx2 silu2s(floatx2 y) {
    floatx2 e;
    e.x = EXP2F(y.x);              // = exp(-x)
    e.y = EXP2F(y.y);
    floatx2 d = e + 1.0f;
    floatx2 r;
    r.x = __uint_as_float(0x7EF311C3u - __float_as_uint(d.x));
    r.y = __uint_as_float(0x7EF311C3u - __float_as_uint(d.y));
    r = r * (2.0f - d * r);
    r = r * (2.0f - d * r);
    return y * r;                  // y * sigmoid(x) = CM * silu(x)
}
__device__ __forceinline__ unsigned cvtpk(float lo, float hi) {
    unsigned r;
    asm("v_cvt_pk_bf16_f32 %0, %1, %2" : "=v"(r) : "v"(lo), "v"(hi));
    return r;
}
// pack two floats to bf16 pair via v_perm_b32 (prep kernel only)
__device__ __forceinline__ unsigned pack2(float a, float b) {
    return __builtin_amdgcn_perm(__float_as_uint(b) + 0x8000u,
                                 __float_as_uint(a) + 0x8000u, 0x07060302u);
}

// ---------------------------------------------------------------------------
// Prep (unchanged): blocks [0,128): Hs/Ht (8 rows each, PRE-SCALED by CM);
// [128,144): weight A-frag pack; [144,146): msum.
// ---------------------------------------------------------------------------
__global__ __launch_bounds__(256) void egcl_prep(
        const float* __restrict__ h, const float* __restrict__ mask,
        const float* __restrict__ ew1, const float* __restrict__ ew2,
        const float* __restrict__ cw1,
        float* __restrict__ Hs, float* __restrict__ Ht,
        unsigned short* __restrict__ W2P, unsigned short* __restrict__ WcP,
        float* __restrict__ msum) {
    __shared__ float sh[8][F_];
    const int blk = blockIdx.x, tid = threadIdx.x;
    if (blk < 128) {
        const int r0 = blk * 8;
        const int col = tid & 127, half = tid >> 7;
#pragma unroll
        for (int rr = 0; rr < 4; ++rr) {
            int row = rr * 2 + half;
            sh[row][col] = h[(r0 + row) * F_ + col] * mask[r0 + row];
        }
        __syncthreads();
        const float* W = ew1 + half * F_ * F_ + col;
        float acc[8] = {0.f, 0.f, 0.f, 0.f, 0.f, 0.f, 0.f, 0.f};
#pragma unroll 8
        for (int k = 0; k < F_; ++k) {
            float w = W[k * F_];
#pragma unroll
            for (int r = 0; r < 8; ++r) acc[r] += sh[r][k] * w;
        }
        float* dst = half ? Ht : Hs;
#pragma unroll
        for (int r = 0; r < 8; ++r) dst[(r0 + r) * F_ + col] = acc[r] * CM;
    } else if (blk < 144) {
        const int wsel = (blk - 128) >> 3;
        const int mt = (blk - 128) & 7;
        const float* src = wsel ? cw1 : ew2;
        unsigned short* dst = wsel ? WcP : W2P;
        const int ln = tid & 63, kk = tid >> 6;       // kk 0..3
        const int qq = ln >> 4, ll = ln & 15;
#pragma unroll
        for (int rep = 0; rep < 2; ++rep) {
            const int krow = kk * 32 + qq * 8 + rep * 4;
            float f0 = src[(krow + 0) * F_ + mt * 16 + ll];
            float f1 = src[(krow + 1) * F_ + mt * 16 + ll];
            float f2 = src[(krow + 2) * F_ + mt * 16 + ll];
            float f3 = src[(krow + 3) * F_ + mt * 16 + ll];
            uint2 u = make_uint2(pack2(f0, f1), pack2(f2, f3));
            *(uint2*)(dst + ((mt * 4 + kk) * 64 + ln) * 8 + rep * 4) = u;
        }
    } else {
        const int bb = blk - 144;
        float v = mask[bb * N_ + tid] + mask[bb * N_ + 256 + tid];
        v += __shfl_xor(v, 1);  v += __shfl_xor(v, 2);
        v += __shfl_xor(v, 4);  v += __shfl_xor(v, 8);
        v += __shfl_xor(v, 16); v += __shfl_xor(v, 32);
        const int wave = tid >> 6, lane = tid & 63;
        if (lane == 0) sh[0][wave] = v;
        __syncthreads();
        if (tid == 0) msum[bb] = sh[0][0] + sh[0][1] + sh[0][2] + sh[0][3];
    }
}

// LDS layout (bytes) — total 138240 (<= 160 KB; 1 block/CU, 8 waves).
#define L_W2   0        // 32768  W2 A-frags (bf16, 128x128)
#define L_WC   32768    // 32768  Wc A-frags
#define L_MS   65536    // 69632  m (bf16), 256 rows x 136 shorts, wave-private
#define L_HB   135168   // 512
#define L_W1R  135680   // 512
#define L_EB2  136192   // 512   eb2 * CM
#define L_CB1  136704   // 512   cb1 * CM
#define L_CW2  137216   // 512   cw2 * INVC
#define L_HIN  137728   // 512
#define L_TOTAL 138240
// Post-loop aliases inside ms (dead after post-loop barrier):
#define L_AGGP (L_MS + 0)     // 4096  per-wave agg partials [8][128]
#define L_CSP  (L_MS + 4096)  // 128   per-wave cs partials [8][3]
#define L_NP   (L_MS + 4224)  // 2048  node-L1 partials [512]
#define L_TL   (L_MS + 6272)  // 512
#define L_AGGT (L_MS + 6784)  // 512

// ---------------------------------------------------------------------------
// Main: 1024 blocks x 512 threads (8 waves); block = one (b,i). Wave w owns
// j-rows [32w, 32w+32): j0 = 32w + l15, j1 = j0 + 16. Zero barriers in the
// p-loop; ms rows are wave-private (same-wave DS ops are in-order).
// ---------------------------------------------------------------------------
__global__ __launch_bounds__(512, 2) void egcl_main(
        const float* __restrict__ h, const float* __restrict__ coord,
        const float* __restrict__ mask,
        const float* __restrict__ eb1, const float* __restrict__ eb2,
        const float* __restrict__ cb1, const float* __restrict__ cw2,
        const float* __restrict__ nw1, const float* __restrict__ nb1,
        const float* __restrict__ nw2, const float* __restrict__ nb2,
        const float* __restrict__ ew1,
        const float* __restrict__ Hs, const float* __restrict__ Ht,
        const unsigned short* __restrict__ W2P,
        const unsigned short* __restrict__ WcP,
        const float* __restrict__ msum,
        float* __restrict__ out_h, float* __restrict__ out_coord) {
    extern __shared__ char smem[];
    unsigned short* W2L = (unsigned short*)(smem + L_W2);
    unsigned short* WcL = (unsigned short*)(smem + L_WC);
    unsigned short* ms  = (unsigned short*)(smem + L_MS);
    float* HB    = (float*)(smem + L_HB);
    float* W1R   = (float*)(smem + L_W1R);
    float* EB2s  = (float*)(smem + L_EB2);
    float* CB1s  = (float*)(smem + L_CB1);
    float* CW2s  = (float*)(smem + L_CW2);
    float* hin   = (float*)(smem + L_HIN);
    float* aggp  = (float*)(smem + L_AGGP);
    float* csp   = (float*)(smem + L_CSP);
    float* np    = (float*)(smem + L_NP);
    float* tl    = (float*)(smem + L_TL);
    float* aggt  = (float*)(smem + L_AGGT);

    const int tid  = threadIdx.x;
    const int wave = tid >> 6, lane = tid & 63;
    const int q = lane >> 4, l15 = lane & 15;
    const int bi = blockIdx.x;
    const int b  = bi >> 9;
    const float mask_i = mask[bi];

    // ---- stage weights (2 x 32768 B) + small vectors into LDS ----
    {
        const uint4* s2 = (const uint4*)W2P;   // 2048 uint4
        const uint4* sc = (const uint4*)WcP;   // 2048 uint4
        uint4* d2 = (uint4*)(smem + L_W2);
        uint4* dc = (uint4*)(smem + L_WC);
#pragma unroll
        for (int t = 0; t < 4; ++t) {
            d2[tid + t * 512] = s2[tid + t * 512];
            dc[tid + t * 512] = sc[tid + t * 512];
        }
    }
    if (tid < F_) {
        HB[tid]   = Ht[bi * F_ + tid] + CM * eb1[tid];  // Ht pre-scaled (prep)
        W1R[tid]  = CM * ew1[2 * F_ * F_ + tid];
        EB2s[tid] = CM * eb2[tid];
        CB1s[tid] = CM * cb1[tid];
        CW2s[tid] = INVC * cw2[tid];
        hin[tid]  = h[bi * F_ + tid] * mask_i;
    }
    const float cmi0 = coord[bi * 3 + 0] * mask_i;
    const float cmi1 = coord[bi * 3 + 1] * mask_i;
    const float cmi2 = coord[bi * 3 + 2] * mask_i;
    __syncthreads();   // the ONLY pre-loop barrier

    const int j0 = wave * 32 + l15;         // local j-rows (fixed per lane)
    const int j1 = j0 + 16;
    unsigned short* msr0 = ms + j0 * MSTRIDE;
    unsigned short* msr1 = ms + j1 * MSTRIDE;

    floatx2 ag2[16];                        // agg partials: [s][pair]
#pragma unroll
    for (int t = 0; t < 16; ++t) ag2[t] = mk2(0.f, 0.f);
    float cs0 = 0.f, cs1 = 0.f, cs2 = 0.f;

    for (int p = 0; p < N_ / TJ; ++p) {
        const int jg0 = b * N_ + p * TJ + j0;
        const int jg1 = jg0 + 16;
        const float mj0 = mask[jg0], mj1 = mask[jg1];
        const float c00 = coord[jg0 * 3 + 0] * mj0;
        const float c01 = coord[jg0 * 3 + 1] * mj0;
        const float c02 = coord[jg0 * 3 + 2] * mj0;
        const float c10 = coord[jg1 * 3 + 0] * mj1;
        const float c11 = coord[jg1 * 3 + 1] * mj1;
        const float c12 = coord[jg1 * 3 + 2] * mj1;
        const float d00 = cmi0 - c00, d01 = cmi1 - c01, d02 = cmi2 - c02;
        const float d10 = cmi0 - c10, d11 = cmi1 - c11, d12 = cmi2 - c12;
        const float f2_0 = mask_i * mj0, f2_1 = mask_i * mj1;
        const float rad0 = (d00 * d00 + d01 * d01 + d02 * d02) * f2_0;
        const float rad1 = (d10 * d10 + d11 * d11 + d12 * d12) * f2_1;
        const floatx2 rr0 = mk2(rad0, rad0), rr1 = mk2(rad1, rad1);
        const floatx2 f220 = mk2(f2_0, f2_0), f221 = mk2(f2_1, f2_1);

        // ---- m1 build: both j-sets, directly into MFMA B-frags ----
        short8 bfr0[4], bfr1[4];
#pragma unroll
        for (int kk = 0; kk < 4; ++kk) {
            const int ko = kk * 32 + q * 8;
            floatx4 hb0 = *(const floatx4*)(HB + ko);
            floatx4 hb1 = *(const floatx4*)(HB + ko + 4);
            floatx4 w10 = *(const floatx4*)(W1R + ko);
            floatx4 w11 = *(const floatx4*)(W1R + ko + 4);
            {
                floatx4 hsA = *(const floatx4*)(Hs + jg0 * F_ + ko);
                floatx4 hsB = *(const floatx4*)(Hs + jg0 * F_ + ko + 4);
                floatx2 y0 = mk2(hsA[0], hsA[1]) + mk2(hb0[0], hb0[1]) + rr0 * mk2(w10[0], w10[1]);
                floatx2 y1 = mk2(hsA[2], hsA[3]) + mk2(hb0[2], hb0[3]) + rr0 * mk2(w10[2], w10[3]);
                floatx2 y2 = mk2(hsB[0], hsB[1]) + mk2(hb1[0], hb1[1]) + rr0 * mk2(w11[0], w11[1]);
                floatx2 y3 = mk2(hsB[2], hsB[3]) + mk2(hb1[2], hb1[3]) + rr0 * mk2(w11[2], w11[3]);
                floatx2 x0 = silu2s(y0), x1 = silu2s(y1);
                floatx2 x2 = silu2s(y2), x3 = silu2s(y3);
                union { short8 s8; unsigned u[4]; } pu;
                pu.u[0] = cvtpk(x0.x, x0.y); pu.u[1] = cvtpk(x1.x, x1.y);
                pu.u[2] = cvtpk(x2.x, x2.y); pu.u[3] = cvtpk(x3.x, x3.y);
                bfr0[kk] = pu.s8;
            }
            {
                floatx4 hsA = *(const floatx4*)(Hs + jg1 * F_ + ko);
                floatx4 hsB = *(const floatx4*)(Hs + jg1 * F_ + ko + 4);
                floatx2 y0 = mk2(hsA[0], hsA[1]) + mk2(hb0[0], hb0[1]) + rr1 * mk2(w10[0], w10[1]);
                floatx2 y1 = mk2(hsA[2], hsA[3]) + mk2(hb0[2], hb0[3]) + rr1 * mk2(w10[2], w10[3]);
                floatx2 y2 = mk2(hsB[0], hsB[1]) + mk2(hb1[0], hb1[1]) + rr1 * mk2(w11[0], w11[1]);
                floatx2 y3 = mk2(hsB[2], hsB[3]) + mk2(hb1[2], hb1[3]) + rr1 * mk2(w11[2], w11[3]);
                floatx2 x0 = silu2s(y0), x1 = silu2s(y1);
                floatx2 x2 = silu2s(y2), x3 = silu2s(y3);
                union { short8 s8; unsigned u[4]; } pu;
                pu.u[0] = cvtpk(x0.x, x0.y); pu.u[1] = cvtpk(x1.x, x1.y);
                pu.u[2] = cvtpk(x2.x, x2.y); pu.u[3] = cvtpk(x3.x, x3.y);
                bfr1[kk] = pu.s8;
            }
        }

        // ---- GEMM1 over 8 fo-blocks, 2 j-sets per A-frag read ----
#pragma unroll
        for (int s = 0; s < 8; ++s) {
            floatx4 bias = *(const floatx4*)(EB2s + s * 16 + q * 4);
            floatx4 a0 = bias, a1 = bias;
#pragma unroll
            for (int kk = 0; kk < 4; ++kk) {
                short8 wf = *(const short8*)(W2L + ((s * 4 + kk) * 64 + lane) * 8);
                a0 = __builtin_amdgcn_mfma_f32_16x16x32_bf16(wf, bfr0[kk], a0, 0, 0, 0);
                a1 = __builtin_amdgcn_mfma_f32_16x16x32_bf16(wf, bfr1[kk], a1, 0, 0, 0);
            }
            floatx2 p00 = silu2s(mk2(a0[0], a0[1])) * f220;
            floatx2 p01 = silu2s(mk2(a0[2], a0[3])) * f220;
            floatx2 p10 = silu2s(mk2(a1[0], a1[1])) * f221;
            floatx2 p11 = silu2s(mk2(a1[2], a1[3])) * f221;
            ag2[2 * s]     += p00 + p10;
            ag2[2 * s + 1] += p01 + p11;
            *(uint2*)(msr0 + s * 16 + q * 4) =
                make_uint2(cvtpk(p00.x, p00.y), cvtpk(p01.x, p01.y));
            *(uint2*)(msr1 + s * 16 + q * 4) =
                make_uint2(cvtpk(p10.x, p10.y), cvtpk(p11.x, p11.y));
        }

        // ---- GEMM2 over 8 fo2-blocks + embed (wave-private) ----
        short8 mfr0[4], mfr1[4];
#pragma unroll
        for (int kk = 0; kk < 4; ++kk) {
            mfr0[kk] = *(const short8*)(msr0 + kk * 32 + q * 8);
            mfr1[kk] = *(const short8*)(msr1 + kk * 32 + q * 8);
        }
        floatx2 esv0 = mk2(0.f, 0.f), esv1 = mk2(0.f, 0.f);
#pragma unroll
        for (int s = 0; s < 8; ++s) {
            floatx4 cb = *(const floatx4*)(CB1s + s * 16 + q * 4);
            floatx4 a0 = cb, a1 = cb;
#pragma unroll
            for (int kk = 0; kk < 4; ++kk) {
                short8 wf = *(const short8*)(WcL + ((s * 4 + kk) * 64 + lane) * 8);
                a0 = __builtin_amdgcn_mfma_f32_16x16x32_bf16(wf, mfr0[kk], a0, 0, 0, 0);
                a1 = __builtin_amdgcn_mfma_f32_16x16x32_bf16(wf, mfr1[kk], a1, 0, 0, 0);
            }
            floatx4 wv = *(const floatx4*)(CW2s + s * 16 + q * 4);  // *INVC
            esv0 += silu2s(mk2(a0[0], a0[1])) * mk2(wv[0], wv[1]);
            esv0 += silu2s(mk2(a0[2], a0[3])) * mk2(wv[2], wv[3]);
            esv1 += silu2s(mk2(a1[0], a1[1])) * mk2(wv[0], wv[1]);
            esv1 += silu2s(mk2(a1[2], a1[3])) * mk2(wv[2], wv[3]);
        }
        float es0 = esv0.x + esv0.y;
        float es1 = esv1.x + esv1.y;
        es0 += __shfl_xor(es0, 16); es0 += __shfl_xor(es0, 32);
        es1 += __shfl_xor(es1, 16); es1 += __shfl_xor(es1, 32);
        if (q == 0) {
            float w0 = es0 * f2_0 * f2_0;
            float w1 = es1 * f2_1 * f2_1;
            cs0 += d00 * w0 + d10 * w1;
            cs1 += d01 * w0 + d11 * w1;
            cs2 += d02 * w0 + d12 * w1;
        }
    }  // p — zero barriers

    // ---- in-wave reductions over j (l15) ----
#pragma unroll
    for (int t = 0; t < 16; ++t) {
        float vx = ag2[t].x, vy = ag2[t].y;
        vx += __shfl_xor(vx, 1); vx += __shfl_xor(vx, 2);
        vx += __shfl_xor(vx, 4); vx += __shfl_xor(vx, 8);
        vy += __shfl_xor(vy, 1); vy += __shfl_xor(vy, 2);
        vy += __shfl_xor(vy, 4); vy += __shfl_xor(vy, 8);
        ag2[t] = mk2(vx, vy);
    }
    cs0 += __shfl_xor(cs0, 1); cs0 += __shfl_xor(cs0, 2);
    cs0 += __shfl_xor(cs0, 4); cs0 += __shfl_xor(cs0, 8);
    cs1 += __shfl_xor(cs1, 1); cs1 += __shfl_xor(cs1, 2);
    cs1 += __shfl_xor(cs1, 4); cs1 += __shfl_xor(cs1, 8);
    cs2 += __shfl_xor(cs2, 1); cs2 += __shfl_xor(cs2, 2);
    cs2 += __shfl_xor(cs2, 4); cs2 += __shfl_xor(cs2, 8);

    __syncthreads();   // all waves done with ms -> safe to alias
    if (l15 == 0) {
#pragma unroll
        for (int s = 0; s < 8; ++s) {
            floatx4 o = {ag2[2 * s].x, ag2[2 * s].y,
                         ag2[2 * s + 1].x, ag2[2 * s + 1].y};
            *(floatx4*)(aggp + wave * F_ + s * 16 + q * 4) = o;
        }
    }
    if (lane == 0) {
        csp[wave * 3 + 0] = cs0;
        csp[wave * 3 + 1] = cs1;
        csp[wave * 3 + 2] = cs2;
    }
    __syncthreads();
    if (tid < F_) {
        float s = 0.f;
#pragma unroll
        for (int w = 0; w < 8; ++w) s += aggp[w * F_ + tid];
        aggt[tid] = s * (mask_i * INVC);   // unwind CM
    }
    __syncthreads();
    // ---- node MLP layer 1: 512 threads, k-split in halves of 64 ----
    {
        const int col = tid & 127, q2 = tid >> 7;   // q2 0..3
        const int half = q2 & 1, kh = q2 >> 1;
        const float* W = nw1 + (half * 128 + kh * 64) * F_ + col;
        const float* src = half ? (aggt + kh * 64) : (hin + kh * 64);
        float s = 0.f;
#pragma unroll 8
        for (int k = 0; k < 64; ++k) s += src[k] * W[k * F_];
        if (half == 0) s *= mask_i;
        np[tid] = s;
    }
    __syncthreads();
    if (tid < F_)
        tl[tid] = fsilu(np[tid] + np[128 + tid] + np[256 + tid] +
                        np[384 + tid] + nb1[tid]);
    __syncthreads();
    if (tid < F_) {
        float s = nb2[tid];
#pragma unroll 8
        for (int k = 0; k < F_; ++k) s += tl[k] * nw2[k * F_ + tid];
        out_h[bi * F_ + tid] = (hin[tid] + s) * mask_i;
    } else if (tid < F_ + 3) {
        int d = tid - F_;
        float denom = mask_i * msum[b] + 1e-10f;
        float cm = (d == 0) ? cmi0 : ((d == 1) ? cmi1 : cmi2);
        float cst = 0.f;
#pragma unroll
        for (int w = 0; w < 8; ++w) cst += csp[w * 3 + d];
        out_coord[bi * 3 + d] = (cm + cst * __builtin_amdgcn_rcpf(denom)) * mask_i;
    }
}

// ---------------------------------------------------------------------------
extern "C" void kernel_launch(void* const* d_in, const int* in_sizes, int n_in,
                              void* d_out, int out_size, void* d_ws, size_t ws_size,
                              hipStream_t stream) {
    const float* h     = (const float*)d_in[0];
    const float* coord = (const float*)d_in[1];
    const float* mask  = (const float*)d_in[2];
    const float* ew1   = (const float*)d_in[3];
    const float* eb1   = (const float*)d_in[4];
    const float* ew2   = (const float*)d_in[5];
    const float* eb2   = (const float*)d_in[6];
    const float* nw1   = (const float*)d_in[7];
    const float* nb1   = (const float*)d_in[8];
    const float* nw2   = (const float*)d_in[9];
    const float* nb2   = (const float*)d_in[10];
    const float* cw1   = (const float*)d_in[11];
    const float* cb1   = (const float*)d_in[12];
    const float* cw2   = (const float*)d_in[13];

    float* Hs = (float*)d_ws;                                   // 131072 f32
    float* Ht = Hs + B_ * N_ * F_;                              // 131072 f32
    unsigned short* W2P = (unsigned short*)(Ht + B_ * N_ * F_); // 16384 u16
    unsigned short* WcP = W2P + F_ * F_;                        // 16384 u16
    float* msum = (float*)(WcP + F_ * F_);                      // 2 f32

    float* out_h = (float*)d_out;
    float* out_coord = out_h + B_ * N_ * F_;

    // raise dynamic-LDS cap once (138240 B > default 64 KB; gfx950 max 160 KB)
    static int attr_done = 0;
    if (!attr_done) {
        (void)hipFuncSetAttribute((const void*)egcl_main,
                                  hipFuncAttributeMaxDynamicSharedMemorySize,
                                  L_TOTAL);
        attr_done = 1;
    }

    egcl_prep<<<146, 256, 0, stream>>>(h, mask, ew1, ew2, cw1,
                                       Hs, Ht, W2P, WcP, msum);
    egcl_main<<<B_ * N_, 512, L_TOTAL, stream>>>(
        h, coord, mask, eb1, eb2, cb1, cw2, nw1, nb1, nw2, nb2, ew1,
        Hs, Ht, W2P, WcP, msum, out_h, out_coord);
}